// Round 5
// baseline (208.132 us; speedup 1.0000x reference)
//
#include <hip/hip_runtime.h>
#include <math.h>

#define MAX_ITERS 100
#define EPS 1e-12f
#define TOL 3e-5f

// v_rcp_f32: <=1 ulp; proven neutral on absmax in R3/R4 (floor is bf16 quantization).
__device__ __forceinline__ float fast_rcp(float x) {
    return __builtin_amdgcn_rcpf(x);
}

// _squash = 0.02 + 0.96*sigmoid(x)
__device__ __forceinline__ float squash(float x) {
    return 0.02f + 0.96f * fast_rcp(1.0f + __expf(-x));
}

// block = 64 = one wave: finest-grained refill (convergence skew balancing),
// per-wave LDS output tile with no cross-wave barrier cost.
// (64,4): VGPR cap 128 (R2 showed cap 64 => spill/AGPR disaster).
__global__ __launch_bounds__(64, 4) void sinkhorn_km_kernel(
    const float* __restrict__ margins,
    const float* __restrict__ W1, const float* __restrict__ b1,
    const float* __restrict__ W2, const float* __restrict__ b2,
    const float* __restrict__ W3, const float* __restrict__ b3,
    const float* __restrict__ Wtau,
    float* __restrict__ out, int B)
{
    // 64 rows x 49 floats = 12544 B. Stage here, then copy out coalesced.
    // ds_write addr = l*49 + k: for fixed k, lanes l and l+32 share a bank
    // (2 lanes/bank = free, m136). Copy-out reads are contiguous b128.
    __shared__ __align__(16) float tile[64 * 49];
    const int l  = threadIdx.x;
    const int wg = blockIdx.x;
    const int b  = wg * 64 + l;
    const bool valid = (b < B);
    float* my = tile + l * 49;

    // ---- load 12 margins (float4, 48B/row)
    float mar[12];
    if (valid) {
        const float4* mp = (const float4*)(margins + (size_t)b * 12);
        float4 m0 = mp[0], m1 = mp[1], m2 = mp[2];
        mar[0] = m0.x; mar[1] = m0.y; mar[2]  = m0.z; mar[3]  = m0.w;
        mar[4] = m1.x; mar[5] = m1.y; mar[6]  = m1.z; mar[7]  = m1.w;
        mar[8] = m2.x; mar[9] = m2.y; mar[10] = m2.z; mar[11] = m2.w;
    } else {
#pragma unroll
        for (int i = 0; i < 12; ++i) mar[i] = 0.5f;  // benign values, keep wave convergent
    }

    // ---- MLP: 12 -> 32 (relu) -> 16 (relu) -> 18; weights wave-uniform (SGPR)
    float h1[32];
#pragma unroll
    for (int o = 0; o < 32; ++o) {
        float acc = b1[o];
#pragma unroll
        for (int i = 0; i < 12; ++i) acc = fmaf(mar[i], W1[i * 32 + o], acc);
        h1[o] = acc > 0.0f ? acc : 0.0f;
    }
    float h2[16];
#pragma unroll
    for (int o = 0; o < 16; ++o) {
        float acc = b2[o];
#pragma unroll
        for (int i = 0; i < 32; ++i) acc = fmaf(h1[i], W2[i * 16 + o], acc);
        h2[o] = acc > 0.0f ? acc : 0.0f;
    }
    float pars[18];
#pragma unroll
    for (int o = 0; o < 18; ++o) {
        float acc = b3[o];
#pragma unroll
        for (int i = 0; i < 16; ++i) acc = fmaf(h2[i], W3[i * 18 + o], acc);
        pars[o] = acc;
    }

    // ---- marginals; mum0/mu0f/corner go straight into the LDS tile
    float shm[6] = {squash(pars[9]),  squash(pars[10]), 1.0f,
                    squash(pars[11]), squash(pars[12]), 1.0f};
    float shf[6] = {squash(pars[13]), squash(pars[14]), 1.0f,
                    squash(pars[15]), squash(pars[16]), 1.0f};
    const float V = __expf(pars[17]);

    float rm[6], cm[6];
#pragma unroll
    for (int j = 0; j < 6; ++j) {
        float Mj = mar[j], Fj = mar[6 + j];
        rm[j] = Mj * shm[j];           // mucm0 (row targets)
        cm[j] = Fj * shf[j];           // muc0f (col targets)
        my[j * 7 + 6] = Mj - rm[j];    // mum0
        my[42 + j]    = Fj - cm[j];    // mu0f
    }
    my[48] = 0.0f;

    // ---- A = exp(einsum('k,kij->ij', pars[0:8], Wtau))
    float A[36];
#pragma unroll
    for (int e = 0; e < 36; ++e) {
        float acc = 0.0f;
#pragma unroll
        for (int k = 0; k < 8; ++k) acc = fmaf(pars[k], Wtau[k * 36 + e], acc);
        A[e] = __expf(acc);
    }

    // ---- Sinkhorn (matrix form, validated R2-R4) with wave-uniform early exit.
    // spread(f) < TOL certifies proximity to the limit (cycle) far below the
    // 3.9e-3 bf16 comparison floor. Cap = reference's 100 iterations.
    for (int t = 0; t < MAX_ITERS; ++t) {
        float f[6];
#pragma unroll
        for (int i = 0; i < 6; ++i) {
            float s = 0.0f;
#pragma unroll
            for (int j = 0; j < 6; ++j) s += A[i * 6 + j];
            f[i] = rm[i] * fast_rcp(s + EPS);
#pragma unroll
            for (int j = 0; j < 6; ++j) A[i * 6 + j] *= f[i];
        }
#pragma unroll
        for (int j = 0; j < 6; ++j) {
            float s = 0.0f;
#pragma unroll
            for (int i = 0; i < 6; ++i) s += A[i * 6 + j];
            float g = cm[j] * fast_rcp(s + EPS);
#pragma unroll
            for (int i = 0; i < 6; ++i) A[i * 6 + j] *= g;
        }
        float fmax = fmaxf(fmaxf(fmaxf(f[0], f[1]), fmaxf(f[2], f[3])),
                           fmaxf(f[4], f[5]));
        float fmin = fminf(fminf(fminf(f[0], f[1]), fminf(f[2], f[3])),
                           fminf(f[4], f[5]));
        if (__all(fmax - fmin <= TOL * fmax)) break;
    }

    // ---- stage A into the tile, then coalesced copy-out
#pragma unroll
    for (int i = 0; i < 6; ++i)
#pragma unroll
        for (int j = 0; j < 6; ++j) my[i * 7 + j] = A[i * 6 + j];

    __syncthreads();  // single-wave block: just an lgkmcnt drain, near-free

    if (wg * 64 + 64 <= B) {
        // fast path: 784 float4 = 12544 B contiguous, 8 cache lines / store
        float4* gdst = (float4*)(out + (size_t)wg * (64 * 49));
        const float4* lsrc = (const float4*)tile;
#pragma unroll
        for (int k = 0; k < 12; ++k) gdst[k * 64 + l] = lsrc[k * 64 + l];
        if (l < 16) gdst[768 + l] = lsrc[768 + l];
    } else if (valid) {
        // partial tail block (not hit at B=524288): scalar fallback
        float* o = out + (size_t)b * 49;
#pragma unroll
        for (int k = 0; k < 49; ++k) o[k] = my[k];
    }

    // V: lane-contiguous store, already coalesced
    if (valid) out[(size_t)B * 49 + b] = V;
}

extern "C" void kernel_launch(void* const* d_in, const int* in_sizes, int n_in,
                              void* d_out, int out_size, void* d_ws, size_t ws_size,
                              hipStream_t stream) {
    const float* margins = (const float*)d_in[0];
    const float* W1   = (const float*)d_in[1];
    const float* b1   = (const float*)d_in[2];
    const float* W2   = (const float*)d_in[3];
    const float* b2   = (const float*)d_in[4];
    const float* W3   = (const float*)d_in[5];
    const float* b3   = (const float*)d_in[6];
    const float* Wtau = (const float*)d_in[7];
    const int B = in_sizes[0] / 12;

    dim3 block(64);
    dim3 grid((B + 63) / 64);
    hipLaunchKernelGGL(sinkhorn_km_kernel, grid, block, 0, stream,
                       margins, W1, b1, W2, b2, W3, b3, Wtau,
                       (float*)d_out, B);
}

// Round 6
// 197.637 us; speedup vs baseline: 1.0531x; 1.0531x over previous
//
#include <hip/hip_runtime.h>
#include <math.h>

#define MAX_ITERS 100
#define EPS 1e-12f
#define TOL 3e-5f

// v_rcp_f32: <=1 ulp; proven absmax-neutral (R3-R5, floor is bf16 quantization).
__device__ __forceinline__ float fast_rcp(float x) {
    return __builtin_amdgcn_rcpf(x);
}

// _squash = 0.02 + 0.96*sigmoid(x)
__device__ __forceinline__ float squash(float x) {
    return 0.02f + 0.96f * fast_rcp(1.0f + __expf(-x));
}

// R4 structure restored: block=256 (R5's block=64 + 12.8KB LDS/block capped
// occupancy at 12 waves/CU and regressed 78->104 us). (256,4): VGPR cap 128;
// compiler has consistently landed at 44-52 VGPR with zero scratch.
__global__ __launch_bounds__(256, 4) void sinkhorn_km_kernel(
    const float* __restrict__ margins,
    const float* __restrict__ W1, const float* __restrict__ b1,
    const float* __restrict__ W2, const float* __restrict__ b2,
    const float* __restrict__ W3, const float* __restrict__ b3,
    const float* __restrict__ Wtau,
    float* __restrict__ out, int B)
{
    // mum0[6], mu0f[6], V in per-thread LDS slots through the loop (R4-proven).
    // Stride 13 (odd): lane l -> banks (13l)%32, bijective, conflict-free.
    __shared__ float side[256 * 13];
    const int tid = threadIdx.x;
    const int b = blockIdx.x * 256 + tid;
    if (b >= B) return;   // no barriers in this kernel -> early return is safe
    float* sd = side + tid * 13;

    // ---- load 12 margins (coalesced float4; 48B/row, 16B aligned)
    const float4* mp = (const float4*)(margins + (size_t)b * 12);
    float4 m0 = mp[0], m1 = mp[1], m2 = mp[2];
    float mar[12] = {m0.x, m0.y, m0.z, m0.w,
                     m1.x, m1.y, m1.z, m1.w,
                     m2.x, m2.y, m2.z, m2.w};

    // ---- MLP: 12 -> 32 (relu) -> 16 (relu) -> 18; weights wave-uniform (SGPR)
    float h1[32];
#pragma unroll
    for (int o = 0; o < 32; ++o) {
        float acc = b1[o];
#pragma unroll
        for (int i = 0; i < 12; ++i) acc = fmaf(mar[i], W1[i * 32 + o], acc);
        h1[o] = acc > 0.0f ? acc : 0.0f;
    }
    float h2[16];
#pragma unroll
    for (int o = 0; o < 16; ++o) {
        float acc = b2[o];
#pragma unroll
        for (int i = 0; i < 32; ++i) acc = fmaf(h1[i], W2[i * 16 + o], acc);
        h2[o] = acc > 0.0f ? acc : 0.0f;
    }
    float pars[18];
#pragma unroll
    for (int o = 0; o < 18; ++o) {
        float acc = b3[o];
#pragma unroll
        for (int i = 0; i < 16; ++i) acc = fmaf(h2[i], W3[i * 18 + o], acc);
        pars[o] = acc;
    }

    // ---- marginals; mum0/mu0f go to LDS, V stays in a register
    float shm[6] = {squash(pars[9]),  squash(pars[10]), 1.0f,
                    squash(pars[11]), squash(pars[12]), 1.0f};
    float shf[6] = {squash(pars[13]), squash(pars[14]), 1.0f,
                    squash(pars[15]), squash(pars[16]), 1.0f};
    const float V = __expf(pars[17]);

    float rm[6], cm[6];
#pragma unroll
    for (int j = 0; j < 6; ++j) {
        float Mj = mar[j], Fj = mar[6 + j];
        rm[j] = Mj * shm[j];         // mucm0 (row targets)
        cm[j] = Fj * shf[j];         // muc0f (col targets)
        sd[j]     = Mj - rm[j];      // mum0
        sd[6 + j] = Fj - cm[j];      // mu0f
    }

    // ---- A0 = exp(einsum('k,kij->ij', pars[0:8], Wtau))
    float A0[36];
#pragma unroll
    for (int e = 0; e < 36; ++e) {
        float acc = 0.0f;
#pragma unroll
        for (int k = 0; k < 8; ++k) acc = fmaf(pars[k], Wtau[k * 36 + e], acc);
        A0[e] = __expf(acc);
    }

    // ---- Sinkhorn in GAUGE-STABILIZED scaling form.
    // A_t = diag(r) A0 diag(c); r = rm/(A0 c), c = cm/(A0^T r) is exactly the
    // reference recursion (EPS relative placement differs by <1e-10 rel).
    // With inconsistent marginals (sum rm != sum cm) the raw r,c diverge as
    // kappa^t (the R1 overflow bug, absmax 0.369); the gauge r*=cn0, c=cn/cn0
    // keeps both O(1) while preserving the product exactly.
    // Loop is ~117 VALU ops/iter vs matrix form's ~192 (no 36-elem A update).
    float c[6] = {1.0f, 1.0f, 1.0f, 1.0f, 1.0f, 1.0f};
    float r[6];
    for (int t = 0; t < MAX_ITERS; ++t) {
#pragma unroll
        for (int i = 0; i < 6; ++i) {
            float s = EPS;
#pragma unroll
            for (int j = 0; j < 6; ++j) s = fmaf(A0[i * 6 + j], c[j], s);
            r[i] = rm[i] * fast_rcp(s);
        }
        float cn[6];
#pragma unroll
        for (int j = 0; j < 6; ++j) {
            float u = EPS;
#pragma unroll
            for (int i = 0; i < 6; ++i) u = fmaf(A0[i * 6 + j], r[i], u);
            cn[j] = cm[j] * fast_rcp(u);
        }
        // gauge: c <- cn/cn0, r <- r*cn0  (product diag(r) A0 diag(c) invariant)
        const float cn0 = cn[0];
        const float g = fast_rcp(cn0);
#pragma unroll
        for (int i = 0; i < 6; ++i) r[i] *= cn0;
        bool conv = true;
#pragma unroll
        for (int j = 0; j < 6; ++j) {
            float cj = cn[j] * g;
            conv = conv && (fabsf(cj - c[j]) <= TOL * cj);
            c[j] = cj;
        }
        // gauge-fixed c converges iff the limit cycle is reached (certifies
        // remaining error ~1e-4 rel, below the 3.9e-3 bf16 floor). Wave-uniform.
        if (__all(conv)) break;
    }

    // ---- epilogue: final A = diag(r) A0 diag(c); scattered stores (R4 path)
    float* o = out + (size_t)b * 49;
#pragma unroll
    for (int i = 0; i < 6; ++i) {
        const float ri = r[i];
#pragma unroll
        for (int j = 0; j < 6; ++j) o[i * 7 + j] = ri * A0[i * 6 + j] * c[j];
        o[i * 7 + 6] = sd[i];
    }
#pragma unroll
    for (int j = 0; j < 6; ++j) o[42 + j] = sd[6 + j];
    o[48] = 0.0f;
    out[(size_t)B * 49 + b] = V;
}

extern "C" void kernel_launch(void* const* d_in, const int* in_sizes, int n_in,
                              void* d_out, int out_size, void* d_ws, size_t ws_size,
                              hipStream_t stream) {
    const float* margins = (const float*)d_in[0];
    const float* W1   = (const float*)d_in[1];
    const float* b1   = (const float*)d_in[2];
    const float* W2   = (const float*)d_in[3];
    const float* b2   = (const float*)d_in[4];
    const float* W3   = (const float*)d_in[5];
    const float* b3   = (const float*)d_in[6];
    const float* Wtau = (const float*)d_in[7];
    const int B = in_sizes[0] / 12;

    dim3 block(256);
    dim3 grid((B + 255) / 256);
    hipLaunchKernelGGL(sinkhorn_km_kernel, grid, block, 0, stream,
                       margins, W1, b1, W2, b2, W3, b3, Wtau,
                       (float*)d_out, B);
}